// Round 1
// baseline (18619.762 us; speedup 1.0000x reference)
//
#include <hip/hip_runtime.h>
#include <hip/hip_bf16.h>
#include <cstdint>

// Neural-ODE RK4 solver, persistent-kernel design.
// B=64 batch rows, X=1024 features, H=4096 hidden, T=64 time points (63 RK4 steps).
// 252 sequential f-evals; each eval = phaseA (hidden) + barrier + phaseB (output) + barrier.

#define NBLK 256
#define NTHR 256
#define B_   64
#define X_   1024
#define H_   4096
#define T_   64
#define NSTEP 63

typedef __bf16 bf16_t;
typedef __attribute__((ext_vector_type(8))) __bf16 bf16x8;
typedef __attribute__((ext_vector_type(4))) float  f32x4;

// ---- workspace layout (bytes) ----
#define WS_GEN   0
#define WS_CNT2  256
#define WS_CNT1  512                        // 8 group counters, 256B apart (index g*64 u32)
#define WS_YIN   4096                       // bf16 [64][1024]  (128 KB)
#define WS_H     (4096 + 131072)            // bf16 [64][4096]  (512 KB)
#define WS_W1P   (4096 + 131072 + 524288)   // bf16 packed W1   (8 MB)
#define WS_W2P   (WS_W1P + 8388608)         // bf16 packed W2   (8 MB)
#define WS_NEED  (WS_W2P + 8388608)

// 2-level device-scope barrier: 8 groups of 32 blocks (by blockIdx&7), then root.
// gen is a monotone epoch; ws barrier region is zeroed by hipMemsetAsync each launch.
__device__ inline void gbar(uint32_t* gen, uint32_t* cnt2, uint32_t* cnt1, uint32_t epoch) {
  __syncthreads();
  if (threadIdx.x == 0) {
    __threadfence();  // release prior global writes (agent scope)
    const int g = blockIdx.x & 7;
    uint32_t old = __hip_atomic_fetch_add(&cnt1[g * 64], 1u, __ATOMIC_ACQ_REL, __HIP_MEMORY_SCOPE_AGENT);
    if (old == 31u) {  // last of this group
      __hip_atomic_store(&cnt1[g * 64], 0u, __ATOMIC_RELEASE, __HIP_MEMORY_SCOPE_AGENT);
      uint32_t o2 = __hip_atomic_fetch_add(cnt2, 1u, __ATOMIC_ACQ_REL, __HIP_MEMORY_SCOPE_AGENT);
      if (o2 == 7u) {  // last group
        __hip_atomic_store(cnt2, 0u, __ATOMIC_RELEASE, __HIP_MEMORY_SCOPE_AGENT);
        __hip_atomic_store(gen, epoch, __ATOMIC_RELEASE, __HIP_MEMORY_SCOPE_AGENT);
      }
    }
    while (__hip_atomic_load(gen, __ATOMIC_ACQUIRE, __HIP_MEMORY_SCOPE_AGENT) < epoch) {
      __builtin_amdgcn_s_sleep(2);
    }
    __threadfence();  // acquire: make others' writes visible
  }
  __syncthreads();
}

__global__ void __launch_bounds__(NTHR, 1) node_rk4_kernel(
    const float* __restrict__ x, const float* __restrict__ ts,
    const float* __restrict__ W1, const float* __restrict__ b1,
    const float* __restrict__ W2, const float* __restrict__ b2,
    float* __restrict__ out, uint8_t* __restrict__ ws)
{
  uint32_t* gen  = (uint32_t*)(ws + WS_GEN);
  uint32_t* cnt2 = (uint32_t*)(ws + WS_CNT2);
  uint32_t* cnt1 = (uint32_t*)(ws + WS_CNT1);
  bf16_t* yin  = (bf16_t*)(ws + WS_YIN);
  bf16_t* hbuf = (bf16_t*)(ws + WS_H);
  bf16_t* W1p  = (bf16_t*)(ws + WS_W1P);
  bf16_t* W2p  = (bf16_t*)(ws + WS_W2P);

  const int tid = threadIdx.x;
  const int b   = blockIdx.x;
  const int w   = tid >> 6;   // wave 0..3
  const int l   = tid & 63;   // lane
  const int lr  = l & 15;
  const int lh  = l >> 4;

  __shared__ float red[4][64][4];  // phase-B cross-wave K-reduction (4 KB)

  // ---- prep: pack W1 slab (cols [16b,16b+16)) into MFMA-B fragment layout ----
  // layout: W1p[b][ks=0..31][lane=0..63][j=0..7]; element = W1[k][16b+nl],
  // k = ks*32 + (lane>>4)*8 + j, nl = lane&15.  idx ordered so WRITES are contiguous.
  for (int idx = tid; idx < 32 * 64 * 8; idx += NTHR) {
    int j    = idx & 7;
    int lane = (idx >> 3) & 63;
    int ks   = idx >> 9;
    int k    = ks * 32 + (lane >> 4) * 8 + j;
    int nl   = lane & 15;
    W1p[(size_t)b * 16384 + idx] = (bf16_t)W1[(size_t)k * H_ + b * 16 + nl];
  }
  // ---- prep: pack W2 quarter: block b packs xg0=b>>2's slab, K-quarter q=b&3 ----
  {
    const int xg0 = b >> 2, q = b & 3;
    for (int idx = tid; idx < 32 * 64 * 8; idx += NTHR) {
      int j    = idx & 7;
      int lane = (idx >> 3) & 63;
      int ks   = idx >> 9;                       // 0..31 within quarter
      int k    = q * 1024 + ks * 32 + (lane >> 4) * 8 + j;
      int nl   = lane & 15;
      W2p[(size_t)xg0 * 65536 + (size_t)q * 16384 + idx] =
          (bf16_t)W2[(size_t)k * X_ + xg0 * 16 + nl];
    }
  }

  // ---- init: RK4 state lives in wave-0 registers of block (xg,mg):
  //      region rows [16*mg,16*mg+16) x cols [16*xg,16*xg+16) ----
  const int xg = b >> 2, mg = b & 3;
  f32x4 yreg = {0.f, 0.f, 0.f, 0.f};
  f32x4 yacc = {0.f, 0.f, 0.f, 0.f};
  if (w == 0) {
    const int col = xg * 16 + lr;
    #pragma unroll
    for (int r = 0; r < 4; r++) {
      const int row = mg * 16 + lh * 4 + r;
      float v = x[(size_t)row * X_ + col];
      yreg[r] = v;
      out[(size_t)row * (T_ * X_) + col] = v;       // pred[:,0,:] = x
      yin[(size_t)row * X_ + col] = (bf16_t)v;      // first GEMM input
    }
  }
  uint32_t epoch = 0;
  gbar(gen, cnt2, cnt1, ++epoch);

  // ---- main time loop ----
  for (int step = 0; step < NSTEP; step++) {
    const float dt = ts[step + 1] - ts[step];
    for (int ev = 0; ev < 4; ev++) {
      // ===== phase A: h[:, 16b:16b+16] = tanh(yin @ W1slab + b1slab) =====
      {
        f32x4 acc = {0.f, 0.f, 0.f, 0.f};
        const bf16_t* arow = yin + (size_t)(w * 16 + lr) * X_ + lh * 8;   // A: row=w*16+lr, k=ks*32+lh*8+j
        const bf16_t* bfr  = W1p + ((size_t)b * 2048 + l) * 8;
        #pragma unroll 4
        for (int ks = 0; ks < 32; ks++) {
          bf16x8 a  = *(const bf16x8*)(arow + ks * 32);
          bf16x8 bb = *(const bf16x8*)(bfr + (size_t)ks * 512);
          acc = __builtin_amdgcn_mfma_f32_16x16x32_bf16(a, bb, acc, 0, 0, 0);
        }
        const int col = b * 16 + lr;
        const float bias = b1[col];
        #pragma unroll
        for (int r = 0; r < 4; r++) {
          const int row = w * 16 + lh * 4 + r;       // C/D: row=(l>>4)*4+r (+16*mtile), col=l&15
          float hv = tanhf(acc[r] + bias);
          hbuf[(size_t)row * H_ + col] = (bf16_t)hv;
        }
      }
      gbar(gen, cnt2, cnt1, ++epoch);

      // ===== phase B: k[16mg:16mg+16, 16xg:16xg+16] = h @ W2slab + b2slab; RK4 update =====
      {
        f32x4 acc = {0.f, 0.f, 0.f, 0.f};
        const bf16_t* arow = hbuf + (size_t)(mg * 16 + lr) * H_ + w * 1024 + lh * 8;  // wave w = K-quarter
        const bf16_t* bfr  = W2p + ((size_t)xg * 8192 + (size_t)w * 2048 + l) * 8;
        #pragma unroll 4
        for (int ks = 0; ks < 32; ks++) {
          bf16x8 a  = *(const bf16x8*)(arow + ks * 32);
          bf16x8 bb = *(const bf16x8*)(bfr + (size_t)ks * 512);
          acc = __builtin_amdgcn_mfma_f32_16x16x32_bf16(a, bb, acc, 0, 0, 0);
        }
        if (w > 0) {
          #pragma unroll
          for (int r = 0; r < 4; r++) red[w][l][r] = acc[r];
        }
        __syncthreads();
        if (w == 0) {
          #pragma unroll
          for (int c = 1; c < 4; c++)
            #pragma unroll
            for (int r = 0; r < 4; r++) acc[r] += red[c][l][r];
          const int col = xg * 16 + lr;
          const float bias = b2[col];
          float kv[4], ypub[4];
          #pragma unroll
          for (int r = 0; r < 4; r++) kv[r] = acc[r] + bias;
          if (ev == 0) {
            #pragma unroll
            for (int r = 0; r < 4; r++) { yacc[r] = yreg[r] + (dt / 6.f) * kv[r]; ypub[r] = yreg[r] + 0.5f * dt * kv[r]; }
          } else if (ev == 1) {
            #pragma unroll
            for (int r = 0; r < 4; r++) { yacc[r] += (dt / 3.f) * kv[r]; ypub[r] = yreg[r] + 0.5f * dt * kv[r]; }
          } else if (ev == 2) {
            #pragma unroll
            for (int r = 0; r < 4; r++) { yacc[r] += (dt / 3.f) * kv[r]; ypub[r] = yreg[r] + dt * kv[r]; }
          } else {
            #pragma unroll
            for (int r = 0; r < 4; r++) { yreg[r] = yacc[r] + (dt / 6.f) * kv[r]; ypub[r] = yreg[r]; }
          }
          #pragma unroll
          for (int r = 0; r < 4; r++) {
            const int row = mg * 16 + lh * 4 + r;
            yin[(size_t)row * X_ + col] = (bf16_t)ypub[r];
            if (ev == 3) out[(size_t)row * (T_ * X_) + (size_t)(step + 1) * X_ + col] = yreg[r];
          }
        }
      }
      gbar(gen, cnt2, cnt1, ++epoch);
    }
  }
}

extern "C" void kernel_launch(void* const* d_in, const int* in_sizes, int n_in,
                              void* d_out, int out_size, void* d_ws, size_t ws_size,
                              hipStream_t stream) {
  const float* x  = (const float*)d_in[0];
  const float* ts = (const float*)d_in[1];
  const float* W1 = (const float*)d_in[2];
  const float* b1 = (const float*)d_in[3];
  const float* W2 = (const float*)d_in[4];
  const float* b2 = (const float*)d_in[5];
  float* out = (float*)d_out;
  if (ws_size < (size_t)WS_NEED) return;  // workspace too small -> clean (visible) failure
  hipMemsetAsync(d_ws, 0, 4096, stream);  // reset barrier state every launch (deterministic)
  node_rk4_kernel<<<NBLK, NTHR, 0, stream>>>(x, ts, W1, b1, W2, b2, out, (uint8_t*)d_ws);
}

// Round 2
// 17755.766 us; speedup vs baseline: 1.0487x; 1.0487x over previous
//
#include <hip/hip_runtime.h>
#include <hip/hip_bf16.h>
#include <cstdint>

// Neural-ODE RK4 solver, persistent weights-stationary kernel.
// B=64, X=1024, H=4096, T=64 (63 RK4 steps, 252 sequential f-evals).
// Per eval: phaseA (h = tanh(y@W1+b1), W1 frags in VGPRs) + global barrier +
//           phaseB (k = h@W2+b2, W2 slab in LDS; RK4 update in regs) + barrier.
// Weights are packed ONCE per launch into CU-local storage; per-eval HBM/L2-miss
// traffic is activations only (~0.7 MB/eval).

#define NBLK 256
#define NTHR 256
#define B_   64
#define X_   1024
#define H_   4096
#define T_   64
#define NSTEP 63

typedef __bf16 bf16_t;
typedef __attribute__((ext_vector_type(8))) __bf16 bf16x8;
typedef __attribute__((ext_vector_type(4))) float  f32x4;

// ---- workspace layout (bytes) ----
#define WS_GEN   0
#define WS_CNT2  256
#define WS_CNT1  512                        // 8 group counters, 256B apart
#define WS_YIN   4096                       // bf16 [64][1024]  (128 KB)
#define WS_H     (4096 + 131072)            // bf16 [64][4096]  (512 KB)
#define WS_NEED  (4096 + 131072 + 524288)

// 2-level device-scope barrier (groups by blockIdx&7 == XCD under round-robin).
__device__ inline void gbar(uint32_t* gen, uint32_t* cnt2, uint32_t* cnt1, uint32_t epoch) {
  __syncthreads();
  if (threadIdx.x == 0) {
    __threadfence();  // release prior global writes
    const int g = blockIdx.x & 7;
    uint32_t old = __hip_atomic_fetch_add(&cnt1[g * 64], 1u, __ATOMIC_ACQ_REL, __HIP_MEMORY_SCOPE_AGENT);
    if (old == 31u) {
      __hip_atomic_store(&cnt1[g * 64], 0u, __ATOMIC_RELEASE, __HIP_MEMORY_SCOPE_AGENT);
      uint32_t o2 = __hip_atomic_fetch_add(cnt2, 1u, __ATOMIC_ACQ_REL, __HIP_MEMORY_SCOPE_AGENT);
      if (o2 == 7u) {
        __hip_atomic_store(cnt2, 0u, __ATOMIC_RELEASE, __HIP_MEMORY_SCOPE_AGENT);
        __hip_atomic_store(gen, epoch, __ATOMIC_RELEASE, __HIP_MEMORY_SCOPE_AGENT);
      }
    }
    while (__hip_atomic_load(gen, __ATOMIC_ACQUIRE, __HIP_MEMORY_SCOPE_AGENT) < epoch) {
      __builtin_amdgcn_s_sleep(2);
    }
    __threadfence();  // acquire
  }
  __syncthreads();
}

__global__ void __launch_bounds__(NTHR, 1) node_rk4_kernel(
    const float* __restrict__ x, const float* __restrict__ ts,
    const float* __restrict__ W1, const float* __restrict__ b1,
    const float* __restrict__ W2, const float* __restrict__ b2,
    float* __restrict__ out, uint8_t* __restrict__ ws)
{
  uint32_t* gen  = (uint32_t*)(ws + WS_GEN);
  uint32_t* cnt2 = (uint32_t*)(ws + WS_CNT2);
  uint32_t* cnt1 = (uint32_t*)(ws + WS_CNT1);
  bf16_t* yin  = (bf16_t*)(ws + WS_YIN);
  bf16_t* hbuf = (bf16_t*)(ws + WS_H);

  const int tid = threadIdx.x;
  const int b   = blockIdx.x;
  const int w   = tid >> 6;   // wave 0..3
  const int l   = tid & 63;   // lane
  const int lr  = l & 15;
  const int lh  = l >> 4;
  const int xg  = b >> 2, mg = b & 3;

  // W2 slab for out-cols [16*xg,16*xg+16), MFMA-B fragment layout:
  // w2s[wq][ks][lane][j] = W2[wq*1024+ks*32+(lane>>4)*8+j][xg*16+(lane&15)]
  __shared__ __align__(16) bf16_t w2s[65536];   // 128 KB
  __shared__ float red[4][64][4];               // phase-B cross-wave K-reduction (4 KB)

  // ---- one-time pack: W2 slab -> LDS (coalesced LDS writes) ----
  for (int idx = tid; idx < 65536; idx += NTHR) {
    int j    = idx & 7;
    int lane = (idx >> 3) & 63;
    int ks   = (idx >> 9) & 31;
    int wq   = idx >> 14;
    int k    = wq * 1024 + ks * 32 + (lane >> 4) * 8 + j;
    w2s[idx] = (bf16_t)W2[(size_t)k * X_ + xg * 16 + (lane & 15)];
  }

  // ---- one-time pack: W1 B-fragments (cols [16b,16b+16)) -> registers ----
  // w1f[ks][j] = W1[ks*32 + lh*8 + j][b*16 + lr]   (layout verified in round 1)
  bf16x8 w1f[32];
  #pragma unroll
  for (int ks = 0; ks < 32; ks++) {
    #pragma unroll
    for (int j = 0; j < 8; j++) {
      w1f[ks][j] = (bf16_t)W1[(size_t)(ks * 32 + lh * 8 + j) * H_ + b * 16 + lr];
    }
  }

  // ---- init: RK4 state in wave-0 registers of block (xg,mg) ----
  f32x4 yreg = {0.f, 0.f, 0.f, 0.f};
  f32x4 yacc = {0.f, 0.f, 0.f, 0.f};
  if (w == 0) {
    const int col = xg * 16 + lr;
    #pragma unroll
    for (int r = 0; r < 4; r++) {
      const int row = mg * 16 + lh * 4 + r;
      float v = x[(size_t)row * X_ + col];
      yreg[r] = v;
      out[(size_t)row * (T_ * X_) + col] = v;       // pred[:,0,:] = x
      yin[(size_t)row * X_ + col] = (bf16_t)v;
    }
  }
  uint32_t epoch = 0;
  gbar(gen, cnt2, cnt1, ++epoch);

  // ---- main time loop ----
  for (int step = 0; step < NSTEP; step++) {
    const float dt = ts[step + 1] - ts[step];
    for (int ev = 0; ev < 4; ev++) {
      // ===== phase A: h[:, 16b:16b+16] = tanh(yin @ W1slab + b1slab) =====
      {
        f32x4 acc = {0.f, 0.f, 0.f, 0.f};
        const bf16_t* arow = yin + (size_t)(w * 16 + lr) * X_ + lh * 8;
        #pragma unroll
        for (int ks = 0; ks < 32; ks++) {
          bf16x8 a = *(const bf16x8*)(arow + ks * 32);
          acc = __builtin_amdgcn_mfma_f32_16x16x32_bf16(a, w1f[ks], acc, 0, 0, 0);
        }
        const int col = b * 16 + lr;
        const float bias = b1[col];
        #pragma unroll
        for (int r = 0; r < 4; r++) {
          const int row = w * 16 + lh * 4 + r;
          float hv = tanhf(acc[r] + bias);
          hbuf[(size_t)row * H_ + col] = (bf16_t)hv;
        }
      }
      gbar(gen, cnt2, cnt1, ++epoch);

      // ===== phase B: k[16mg:+16, 16xg:+16] = h @ W2slab + b2; RK4 update =====
      {
        f32x4 acc = {0.f, 0.f, 0.f, 0.f};
        const bf16_t* arow = hbuf + (size_t)(mg * 16 + lr) * H_ + w * 1024 + lh * 8;
        const bf16_t* bfr  = w2s + ((size_t)w * 2048 + l) * 8;
        #pragma unroll
        for (int ks = 0; ks < 32; ks++) {
          bf16x8 a  = *(const bf16x8*)(arow + ks * 32);
          bf16x8 bb = *(const bf16x8*)(bfr + (size_t)ks * 512);
          acc = __builtin_amdgcn_mfma_f32_16x16x32_bf16(a, bb, acc, 0, 0, 0);
        }
        if (w > 0) {
          #pragma unroll
          for (int r = 0; r < 4; r++) red[w][l][r] = acc[r];
        }
        __syncthreads();
        if (w == 0) {
          #pragma unroll
          for (int c = 1; c < 4; c++)
            #pragma unroll
            for (int r = 0; r < 4; r++) acc[r] += red[c][l][r];
          const int col = xg * 16 + lr;
          const float bias = b2[col];
          float kv[4], ypub[4];
          #pragma unroll
          for (int r = 0; r < 4; r++) kv[r] = acc[r] + bias;
          if (ev == 0) {
            #pragma unroll
            for (int r = 0; r < 4; r++) { yacc[r] = yreg[r] + (dt / 6.f) * kv[r]; ypub[r] = yreg[r] + 0.5f * dt * kv[r]; }
          } else if (ev == 1) {
            #pragma unroll
            for (int r = 0; r < 4; r++) { yacc[r] += (dt / 3.f) * kv[r]; ypub[r] = yreg[r] + 0.5f * dt * kv[r]; }
          } else if (ev == 2) {
            #pragma unroll
            for (int r = 0; r < 4; r++) { yacc[r] += (dt / 3.f) * kv[r]; ypub[r] = yreg[r] + dt * kv[r]; }
          } else {
            #pragma unroll
            for (int r = 0; r < 4; r++) { yreg[r] = yacc[r] + (dt / 6.f) * kv[r]; ypub[r] = yreg[r]; }
          }
          #pragma unroll
          for (int r = 0; r < 4; r++) {
            const int row = mg * 16 + lh * 4 + r;
            yin[(size_t)row * X_ + col] = (bf16_t)ypub[r];
            if (ev == 3) out[(size_t)row * (T_ * X_) + (size_t)(step + 1) * X_ + col] = yreg[r];
          }
        }
      }
      gbar(gen, cnt2, cnt1, ++epoch);
    }
  }
}

extern "C" void kernel_launch(void* const* d_in, const int* in_sizes, int n_in,
                              void* d_out, int out_size, void* d_ws, size_t ws_size,
                              hipStream_t stream) {
  const float* x  = (const float*)d_in[0];
  const float* ts = (const float*)d_in[1];
  const float* W1 = (const float*)d_in[2];
  const float* b1 = (const float*)d_in[3];
  const float* W2 = (const float*)d_in[4];
  const float* b2 = (const float*)d_in[5];
  float* out = (float*)d_out;
  uint8_t* ws = (uint8_t*)d_ws;
  if (ws_size < (size_t)WS_NEED) return;
  hipMemsetAsync(d_ws, 0, 4096, stream);  // reset barrier state every launch

  // 135 KB LDS forces exactly 1 block/CU; cooperative launch guarantees all 256
  // blocks are co-resident for the global barrier.
  void* args[] = {(void*)&x, (void*)&ts, (void*)&W1, (void*)&b1,
                  (void*)&W2, (void*)&b2, (void*)&out, (void*)&ws};
  hipError_t err = hipLaunchCooperativeKernel((void*)node_rk4_kernel,
                                              dim3(NBLK), dim3(NTHR), args, 0, stream);
  if (err != hipSuccess) {
    // fallback: plain launch (same grid; dispatcher round-robins 256 blocks
    // onto 256 CUs — the round-1 kernel relied on the same property)
    node_rk4_kernel<<<dim3(NBLK), dim3(NTHR), 0, stream>>>(x, ts, W1, b1, W2, b2, out, ws);
  }
}

// Round 4
// 7591.935 us; speedup vs baseline: 2.4526x; 2.3388x over previous
//
#include <hip/hip_runtime.h>
#include <hip/hip_bf16.h>
#include <cstdint>

// Neural-ODE RK4, persistent weights-in-register kernel, v4.
// v3 post-mortem: replay-only divergence = memory race in the hand-rolled
// barrier (inline-asm stores invisible to compiler waitcnt insertion; acquire
// relied on fence lowering). v4 makes the protocol explicit at ISA level and
// shrinks barriers to 64-block row-groups (the 4 row-groups are independent
// ODE solves: batch rows never interact).
//
// Protocol per barrier (group = 64 blocks sharing mg):
//   release: s_waitcnt vmcnt(0) in EVERY thread (drains each wave's coherent
//            write-through stores) -> __syncthreads -> flag store sc0 sc1
//   detect : wave 0's 64 lanes each spin one group flag (sc0 sc1 loads)
//   acquire: __syncthreads -> s_waitcnt vmcnt(0); buffer_inv sc0 sc1
//            (LLVM's agent-acquire sequence, emitted explicitly)
// All cross-block data stores are sc0 sc1 write-through => no dirty L2 lines
// anywhere => no wbl2 needed on release; buffer_inv cannot lose data.

#define NBLK 256
#define NTHR 256
#define X_   1024
#define H_   4096
#define T_   64
#define NSTEP 63
#define FSTRIDE 16   // u32 stride between flag slots (64 B apart)

typedef __bf16 bf16_t;
typedef __attribute__((ext_vector_type(8))) __bf16 bf16x8;
typedef __attribute__((ext_vector_type(4))) float  f32x4;
typedef __attribute__((ext_vector_type(2))) uint32_t u32x2;

// ---- workspace layout (bytes) ----
#define WS_FLAGS 0                          // 256 slots * 64B = 16 KB
#define WS_YIN   16384                      // bf16 [64][1024]  (128 KB)
#define WS_H     (16384 + 131072)           // bf16 [64][4096]  (512 KB)
#define WS_NEED  (16384 + 131072 + 524288)

// -------- coherent write-through stores (never leave dirty L2 lines) --------
__device__ inline void store_coh_b16(bf16_t* p, float v) {
  uint32_t d = (uint32_t)__builtin_bit_cast(uint16_t, (bf16_t)v);
  asm volatile("global_store_short %0, %1, off sc0 sc1" :: "v"(p), "v"(d) : "memory");
}
__device__ inline void store_coh_f32(float* p, float v) {
  asm volatile("global_store_dword %0, %1, off sc0 sc1" :: "v"(p), "v"(v) : "memory");
}
__device__ inline void store_coh_b64(bf16_t* p, u32x2 v) {
  asm volatile("global_store_dwordx2 %0, %1, off sc0 sc1" :: "v"(p), "v"(v) : "memory");
}
__device__ inline void store_flag(uint32_t* p, uint32_t v) {
  asm volatile("global_store_dword %0, %1, off sc0 sc1" :: "v"(p), "v"(v) : "memory");
}
__device__ inline uint32_t load_flag(const uint32_t* p) {
  uint32_t v;
  asm volatile("global_load_dword %0, %1, off sc0 sc1\n\ts_waitcnt vmcnt(0)"
               : "=v"(v) : "v"(p) : "memory");
  return v;
}

// -------- 64-block group barrier (group = row-group mg) --------
__device__ inline void gbar(uint32_t* flags, int grp, int g16, uint32_t epoch) {
  // release: drain THIS wave's outstanding (inline-asm) stores, then rendezvous
  asm volatile("s_waitcnt vmcnt(0)" ::: "memory");
  __syncthreads();
  const int t = threadIdx.x;
  if (t == 0) store_flag(&flags[(grp * 64 + g16) * FSTRIDE], epoch);
  if (t < 64) {
    while (load_flag(&flags[(grp * 64 + t) * FSTRIDE]) < epoch)
      __builtin_amdgcn_s_sleep(1);
  }
  __syncthreads();
  // acquire: explicit LLVM agent-acquire sequence; subsequent plain loads refetch
  asm volatile("s_waitcnt vmcnt(0)\n\tbuffer_inv sc0 sc1" ::: "memory");
}

__global__ void __launch_bounds__(NTHR, 1) node_rk4_kernel(
    const float* __restrict__ x, const float* __restrict__ ts,
    const float* __restrict__ W1, const float* __restrict__ b1,
    const float* __restrict__ W2, const float* __restrict__ b2,
    float* __restrict__ out, uint8_t* __restrict__ ws)
{
  uint32_t* flags = (uint32_t*)(ws + WS_FLAGS);
  bf16_t* yin  = (bf16_t*)(ws + WS_YIN);
  bf16_t* hbuf = (bf16_t*)(ws + WS_H);

  const int tid = threadIdx.x;
  const int b   = blockIdx.x;
  const int w   = tid >> 6;    // wave 0..3
  const int l   = tid & 63;
  const int lr  = l & 15;
  const int lh  = l >> 4;
  const int g16 = b >> 2;      // 0..63: phase-A 64-hcol group / phase-B 16-xcol group
  const int mg  = b & 3;       // 0..3 : row group (rows [16*mg, +16)) for BOTH phases

  __shared__ float red[4][64][4];   // per-wave transpose (A) / cross-wave K-reduce (B)
  __shared__ float tsl[T_];

  if (tid < T_) tsl[tid] = ts[tid];

  // ---- pack W1 B-fragments: wave w owns h-cols [g16*64 + w*16, +16), full K ----
  bf16x8 w1f[32];
  #pragma unroll
  for (int ks = 0; ks < 32; ks++)
    #pragma unroll
    for (int j = 0; j < 8; j++)
      w1f[ks][j] = (bf16_t)W1[(size_t)(ks * 32 + lh * 8 + j) * H_ + g16 * 64 + w * 16 + lr];

  // ---- pack W2 B-fragments: out-cols [g16*16, +16), wave w owns K-quarter w ----
  bf16x8 w2f[32];
  #pragma unroll
  for (int ks = 0; ks < 32; ks++)
    #pragma unroll
    for (int j = 0; j < 8; j++)
      w2f[ks][j] = (bf16_t)W2[(size_t)(w * 1024 + ks * 32 + lh * 8 + j) * X_ + g16 * 16 + lr];

  // ---- per-thread epilogue mapping (one output element per thread) ----
  const int erow  = tid >> 4;                 // 0..15 within tile
  const int ecol  = tid & 15;
  const int elane = (erow >> 2) * 16 + ecol;  // C/D: col=lane&15, row=(lane>>4)*4+reg
  const int ereg  = erow & 3;
  const int grow  = mg * 16 + erow;           // global row (batch)
  const int gcolX = g16 * 16 + ecol;          // global X column
  const float bias1 = b1[g16 * 64 + w * 16 + lr];  // phase-A per-lane bias (col=lr)
  const float bias2 = b2[gcolX];

  // ---- RK4 state: 1 element per thread, in registers for the whole solve ----
  float y   = x[(size_t)grow * X_ + gcolX];
  float yac = 0.f;
  store_coh_f32(&out[(size_t)grow * (T_ * X_) + gcolX], y);   // pred[:,0,:] = x
  store_coh_b16(&yin[(size_t)grow * X_ + gcolX], y);

  uint32_t epoch = 0;
  gbar(flags, mg, g16, ++epoch);

  for (int step = 0; step < NSTEP; step++) {
    const float dt = tsl[step + 1] - tsl[step];
    for (int ev = 0; ev < 4; ev++) {
      // ===== phase A: h[16mg:+16, g16*64:+64] = tanh(yin @ W1 + b1) =====
      {
        f32x4 acc = {0.f, 0.f, 0.f, 0.f};
        const bf16_t* arow = yin + (size_t)(mg * 16 + lr) * X_ + lh * 8;
        #pragma unroll
        for (int ks = 0; ks < 32; ks++) {
          bf16x8 a = *(const bf16x8*)(arow + ks * 32);
          acc = __builtin_amdgcn_mfma_f32_16x16x32_bf16(a, w1f[ks], acc, 0, 0, 0);
        }
        #pragma unroll
        for (int r = 0; r < 4; r++) acc[r] = tanhf(acc[r] + bias1);
        // wave-private transpose through LDS -> one 8B coherent store per lane
        *(f32x4*)&red[w][l][0] = acc;
        const int trow = l >> 2;          // 0..15
        const int tc0  = (l & 3) * 4;     // 4 consecutive cols
        float v0 = red[w][(trow >> 2) * 16 + tc0 + 0][trow & 3];
        float v1 = red[w][(trow >> 2) * 16 + tc0 + 1][trow & 3];
        float v2 = red[w][(trow >> 2) * 16 + tc0 + 2][trow & 3];
        float v3 = red[w][(trow >> 2) * 16 + tc0 + 3][trow & 3];
        u32x2 pk;
        pk[0] = (uint32_t)__builtin_bit_cast(uint16_t, (bf16_t)v0)
              | ((uint32_t)__builtin_bit_cast(uint16_t, (bf16_t)v1) << 16);
        pk[1] = (uint32_t)__builtin_bit_cast(uint16_t, (bf16_t)v2)
              | ((uint32_t)__builtin_bit_cast(uint16_t, (bf16_t)v3) << 16);
        store_coh_b64(&hbuf[(size_t)(mg * 16 + trow) * H_ + g16 * 64 + w * 16 + tc0], pk);
      }
      gbar(flags, mg, g16, ++epoch);

      // ===== phase B: k[16mg:+16, g16*16:+16] = h @ W2 + b2; RK4 update =====
      {
        f32x4 acc = {0.f, 0.f, 0.f, 0.f};
        const bf16_t* brow = hbuf + (size_t)(mg * 16 + lr) * H_ + w * 1024 + lh * 8;
        #pragma unroll
        for (int ks = 0; ks < 32; ks++) {
          bf16x8 a = *(const bf16x8*)(brow + ks * 32);
          acc = __builtin_amdgcn_mfma_f32_16x16x32_bf16(a, w2f[ks], acc, 0, 0, 0);
        }
        *(f32x4*)&red[w][l][0] = acc;     // cross-wave K reduction
        __syncthreads();
        float kv = red[0][elane][ereg] + red[1][elane][ereg]
                 + red[2][elane][ereg] + red[3][elane][ereg] + bias2;
        float ypub;
        if (ev == 0)      { yac = y + dt * (1.f / 6.f) * kv; ypub = y + 0.5f * dt * kv; }
        else if (ev == 1) { yac += dt * (1.f / 3.f) * kv;    ypub = y + 0.5f * dt * kv; }
        else if (ev == 2) { yac += dt * (1.f / 3.f) * kv;    ypub = y + dt * kv; }
        else              { y = yac + dt * (1.f / 6.f) * kv; ypub = y; }
        store_coh_b16(&yin[(size_t)grow * X_ + gcolX], ypub);
        if (ev == 3)
          store_coh_f32(&out[(size_t)grow * (T_ * X_) + (size_t)(step + 1) * X_ + gcolX], y);
      }
      gbar(flags, mg, g16, ++epoch);
    }
  }
}

extern "C" void kernel_launch(void* const* d_in, const int* in_sizes, int n_in,
                              void* d_out, int out_size, void* d_ws, size_t ws_size,
                              hipStream_t stream) {
  const float* x  = (const float*)d_in[0];
  const float* ts = (const float*)d_in[1];
  const float* W1 = (const float*)d_in[2];
  const float* b1 = (const float*)d_in[3];
  const float* W2 = (const float*)d_in[4];
  const float* b2 = (const float*)d_in[5];
  float* out = (float*)d_out;
  uint8_t* ws = (uint8_t*)d_ws;
  if (ws_size < (size_t)WS_NEED) return;
  hipMemsetAsync(d_ws, 0, 16384, stream);  // reset flag lines every launch

  void* args[] = {(void*)&x, (void*)&ts, (void*)&W1, (void*)&b1,
                  (void*)&W2, (void*)&b2, (void*)&out, (void*)&ws};
  hipError_t err = hipLaunchCooperativeKernel((void*)node_rk4_kernel,
                                              dim3(NBLK), dim3(NTHR), args, 0, stream);
  if (err != hipSuccess) {
    node_rk4_kernel<<<dim3(NBLK), dim3(NTHR), 0, stream>>>(x, ts, W1, b1, W2, b2, out, ws);
  }
}